// Round 2
// baseline (93.347 us; speedup 1.0000x reference)
//
#include <hip/hip_runtime.h>

// LatticeGen: permutohedral-lattice splat, reduced form.
// bary degenerates to [1,0,0]; out[b,r,c,ch] = sum_n feat[b,ch,n]*[bin(n)==(r,c)], duplicated.
// B=32, N=16384, grid G=256 (S=768, D1=3).
// Binning bit-matches numpy's plain (non-FMA) f32 arithmetic via
// `#pragma clang fp contract(off)` (__f*_rn are NOT contraction barriers — R2).
// R5: LDS-private output-tiled histogram. R8: offset-independent counting
// sort (ring keyed by absolute 4-row band of k0). R9/R11: 8B uint2 bf16
// payload entries. R10 FAILED: grid.sync ~70us on 8-XCD MI355X.
// R13: TR=4, NSLOT=128. R14: zero global coordination, no ws init.
// R15: tile chunk->wave ownership (no per-entry LDS search, no serial
// prefix); empty bands store zeros from registers. 92.4 -> 88.7 us.
// R16 (this round): prep's per-point scattered 8B bucket stores (64 lanes ->
// ~40 distinct 49KB-strided lines per store instr; partial-line RFO into
// poisoned HBM lines; atomic->store dep chain in the point loop) replaced by
// LDS slot-sorted staging: count (atomicAdd, as before) -> 2-wave shfl
// prefix over the 128 slot counts -> scatter entries into an 8KB LDS ebuf ->
// per-slot COALESCED copy-out (runs are 64B-aligned, avg exactly 1 line).
// tile: hoist T==0 check above the 12KB hist zeroing (1280/2080 blocks
// empty), one fewer barrier on the empty path.
// NOTE: ~55 us of every dur_us is harness overhead (0xAA poison of 256MiB
// ws + 50MB out + 12MB input restores @ ~6.3 TB/s) — untouchable floor.

#define GV 256
#define NB 16384
#define BB 32
#define TR 4                         // rows per tile block
#define NSLOT 128                    // bucket ring slots per batch
#define NCH 16                       // prep chunks (blocks) per batch
#define NJ (GV / TR + 1)             // 65 tile blocks per batch (+1 for misalign)
#define TILE_FLOATS (TR * GV * 3)    // 3072 floats = 12 KB
#define ROWF4 (GV * 3 / 4)           // 192 float4 per output row
#define CAP 384                      // entries per (block,slot) sub-bucket
                                     //   (peak chunk-slot ~135 for this data; 2.8x margin)
#define PPT 4                        // points per thread in prep

typedef float vfloat4 __attribute__((ext_vector_type(4)));

__device__ __forceinline__ void lattice_point(const float* __restrict__ pc,
                                              long base, int n,
                                              int& k0o, int& k1o, int& r0o, int& r1o) {
#pragma clang fp contract(off)
  const float S6 = 2.449489742783178f;   // float32(sqrt(6.0))
  const float CA = 2.0f / S6;
  const float CB = -1.0f / S6;

  float p0 = pc[base + 0 * (long)NB + n];
  float p1 = pc[base + 1 * (long)NB + n];
  float p2 = pc[base + 2 * (long)NB + n];

  // elevated = E @ p: plain f32, left-to-right, no FMA — matches np.einsum
  float e0 = CA * p0 + CB * p1 + CB * p2;
  float e1 = CB * p0 + CA * p1 + CB * p2;
  float e2 = CB * p0 + CB * p1 + CA * p2;

  float q0 = rintf(e0 / 3.0f);
  float q1 = rintf(e1 / 3.0f);
  float q2 = rintf(e2 / 3.0f);
  int k0 = (int)q0, k1 = (int)q1, k2 = (int)q2;

  float m0 = e0 - q0 * 3.0f;
  float m1 = e1 - q1 * 3.0f;
  float m2 = e2 - q2 * 3.0f;

  // stable descending rank
  int rank0 = (m1 > m0) + (m2 > m0);
  int rank1 = (m0 > m1) + (m2 > m1) + (m0 == m1);
  int rs = k0 + k1 + k2;

  if (rs > 0) {
    int t = 3 - rs;
    if (rank0 >= t) { k0 -= 1; rank0 -= 3; }
    if (rank1 >= t) { k1 -= 1; rank1 -= 3; }
  } else if (rs < 0) {
    int t = -rs;
    if (rank0 < t) { k0 += 1; rank0 += 3; }
    if (rank1 < t) { k1 += 1; rank1 += 3; }
  }
  rank0 += rs; rank1 += rs;   // final rank in [0,2]

  k0o = k0; k1o = k1; r0o = rank0; r1o = rank1;   // gl = 3*k
}

// off (= min_n 3*k_i - rank_i) -> shift in k units: s = (off+pick)/3, exact.
__device__ __forceinline__ int k_shift(int off) {
  int pick = ((-off) % 3 + 3) % 3;   // off+pick is an exact multiple of 3
  return (off + pick) / 3;
}

__device__ __forceinline__ unsigned int bf16_rne(float f) {
  unsigned int u = __float_as_uint(f);
  return (u + 0x7FFFu + ((u >> 16) & 1u)) >> 16;
}

// Pass 1: lattice -> per-block mins + counting-sort into private sub-buckets.
// 512 blocks; block (b,chunk) owns 1024 consecutive points, 4/thread.
// R16: entries staged slot-sorted in LDS, then copied out per slot with
// full-line coalesced writes (each (chunk,slot) run starts 64B-aligned).
// Writes: buckets[b][m][chunk][0..cnt), cntArr[b][chunk][m] (all 128),
// mins[b][chunk][0..1]. Everything read later is written here — no init.
__global__ void __launch_bounds__(256) prep_kernel(const float* __restrict__ pc,
                                                   const float* __restrict__ feat,
                                                   int* __restrict__ mins,
                                                   int* __restrict__ cntArr,
                                                   uint2* __restrict__ buckets) {
  int i = blockIdx.x;
  int b = (i & 7) + 8 * ((i >> 3) & 3);   // XCD-affinity: same-batch blocks share i%8
  int chunk = i >> 5;                     // 0..15
  int n0 = chunk * 1024 + threadIdx.x;

  __shared__ unsigned int cnt[NSLOT];
  __shared__ unsigned int pref[NSLOT];
  __shared__ uint2 ebuf[1024];           // 8 KB slot-sorted staging
  __shared__ int s0w[4], s1w[4];
  __shared__ unsigned int w0tot;
  if (threadIdx.x < NSLOT) cnt[threadIdx.x] = 0;
  __syncthreads();

  long pcB = (long)b * 3 * NB;
  long bktB = ((long)b * NSLOT * NCH + chunk) * CAP;  // + m*NCH*CAP below
  int mloc0 = 0x7FFFFFFF, mloc1 = 0x7FFFFFFF;

  int mA[PPT];
  unsigned int slA[PPT];
  uint2 entA[PPT];

#pragma unroll
  for (int p = 0; p < PPT; ++p) {
    int n = n0 + p * 256;
    int k0, k1, r0, r1;
    lattice_point(pc, pcB, n, k0, k1, r0, r1);

    int kb = k0 + 8192;                   // >= 0
    int m = (kb >> 2) & (NSLOT - 1);      // 4-row-band ring slot

    long fbB = pcB + n;
    unsigned int b0 = bf16_rne(feat[fbB]);
    unsigned int b1 = bf16_rne(feat[fbB + NB]);
    unsigned int b2 = bf16_rne(feat[fbB + 2 * NB]);
    uint2 ent;
    // meta: kb&3 (2b) | k1+512 (10b) | pad (1b) | bf16(f0) (16b)
    ent.x = (unsigned int)(kb & 3) | ((unsigned int)(k1 + 512) << 2) | (b0 << 13);
    ent.y = b1 | (b2 << 16);

    mA[p] = m;
    entA[p] = ent;
    slA[p] = atomicAdd(&cnt[m], 1u);      // order within slot (fp-atomic-order
                                          // in tile is nondeterministic anyway)
    mloc0 = min(mloc0, 3 * k0 - r0);
    mloc1 = min(mloc1, 3 * k1 - r1);
  }
  __syncthreads();   // cnt totals final

  // exclusive prefix over the 128 slot counts: per-wave shfl scan (waves 0,1)
  {
    unsigned int orig = 0, v = 0;
    if (threadIdx.x < NSLOT) { orig = cnt[threadIdx.x]; v = orig; }
    for (int d = 1; d < 64; d <<= 1) {
      unsigned int t = __shfl_up(v, d);
      if ((threadIdx.x & 63) >= d) v += t;
    }
    if (threadIdx.x == 63) w0tot = v;     // total of slots 0..63
    __syncthreads();
    if (threadIdx.x >= 64 && threadIdx.x < NSLOT) v += w0tot;
    if (threadIdx.x < NSLOT) pref[threadIdx.x] = v - orig;
  }
  __syncthreads();

  // slot-sorted scatter into LDS (total is exactly 1024 entries)
#pragma unroll
  for (int p = 0; p < PPT; ++p)
    ebuf[pref[mA[p]] + slA[p]] = entA[p];
  __syncthreads();

  // coalesced copy-out: wave wv owns slots {wv, wv+4, ...}; each run is
  // contiguous and 64B-aligned (CAP*8 = 3072B sub-bucket pitch).
  {
    int wv = threadIdx.x >> 6, lane = threadIdx.x & 63;
    for (int s = wv; s < NSLOT; s += 4) {
      int c = (int)cnt[s];                // wave-uniform LDS broadcast
      unsigned int p0 = pref[s];
      long gb = bktB + (long)s * (NCH * CAP);
      for (int t = lane; t < c; t += 64)
        buckets[gb + t] = ebuf[p0 + t];
    }
  }

  // block-level mins of (3k - rank)
  for (int off = 32; off > 0; off >>= 1) {
    mloc0 = min(mloc0, __shfl_down(mloc0, off));
    mloc1 = min(mloc1, __shfl_down(mloc1, off));
  }
  int lane = threadIdx.x & 63, wv = threadIdx.x >> 6;
  if (lane == 0) { s0w[wv] = mloc0; s1w[wv] = mloc1; }
  __syncthreads();   // s0w/s1w visible
  if (threadIdx.x == 0) {
    mins[(b * NCH + chunk) * 2 + 0] = min(min(s0w[0], s0w[1]), min(s0w[2], s0w[3]));
    mins[(b * NCH + chunk) * 2 + 1] = min(min(s1w[0], s1w[1]), min(s1w[2], s1w[3]));
  }
  if (threadIdx.x < NSLOT)
    cntArr[(b * NCH + chunk) * NSLOT + threadIdx.x] = (int)cnt[threadIdx.x];
}

// Pass 2: one block per (batch, absolute 4-row band). Wave wv owns chunks
// {wv, wv+4, wv+8, wv+12}; plain strided scan per chunk (no per-entry
// search, no prefix sum). LDS hist; float4 store x2. T==0 blocks (most)
// skip the hist entirely and store zeros from registers.
__global__ void __launch_bounds__(256) tile_kernel(const int* __restrict__ mins,
                                                   const int* __restrict__ cntArr,
                                                   const uint2* __restrict__ buckets,
                                                   float* __restrict__ out, long half) {
  __shared__ float hist[TILE_FLOATS];  // [TR][GV][3], 12 KB
  __shared__ int sOff[2];
  __shared__ int scnt[NCH];

  int i = blockIdx.x;                    // 0..BB*NJ-1
  int w = i & 31;
  int b = (w & 7) + 8 * ((w >> 3) & 3);  // matches prep's i%8 XCD affinity
  int j = i >> 5;                        // 0..NJ-1

  // reduce the 16 per-block mins (threads 0,1: one dim each)
  if (threadIdx.x < 2) {
    int mn = 0x7FFFFFFF;
#pragma unroll
    for (int c = 0; c < NCH; ++c)
      mn = min(mn, mins[(b * NCH + c) * 2 + threadIdx.x]);
    sOff[threadIdx.x] = mn;
  }
  __syncthreads();                       // sOff visible (m depends on it)

  int s0b = k_shift(sOff[0]) + 8192;     // row shift in k units, biased
  int s1b = k_shift(sOff[1]) + 512;      // col shift, biased to match entry pack
  int kt = (s0b >> 2) + j;               // this block's absolute 4-row band
  int m = kt & (NSLOT - 1);
  int rlo = 4 * kt - s0b;                // output row of hist row 0, in [-3, 256+3]

  if (threadIdx.x < NCH)                 // stage chunk counts
    scnt[threadIdx.x] = cntArr[(b * NCH + threadIdx.x) * NSLOT + m];
  __syncthreads();

  int T = 0;
#pragma unroll
  for (int c = 0; c < NCH; ++c) T += scnt[c];   // cheap broadcast reads

  long g0 = ((long)b * GV) * GV * 3;

  if (T > 0) {                           // block-uniform branch: barriers legal
    for (int t = threadIdx.x; t < TILE_FLOATS; t += 256) hist[t] = 0.0f;
    __syncthreads();

    int wv = threadIdx.x >> 6, lane = threadIdx.x & 63;
    long base = ((long)b * NSLOT + m) * (NCH * CAP);
#pragma unroll
    for (int cq = 0; cq < NCH / 4; ++cq) {
      int c = wv + cq * 4;
      int cnt = scnt[c];                 // wave-uniform LDS broadcast
      long cb = base + (long)c * CAP;
      for (int t = lane; t < cnt; t += 64) {
        uint2 e = buckets[cb + t];       // coalesced 8B within the run
        int rr = e.x & 3;
        int cc = (int)((e.x >> 2) & 1023) - s1b;  // >= 0 by construction of off1
        if (cc < GV) {                            // JAX scatter 'drop'
          float f0 = __uint_as_float((e.x >> 13) << 16);
          float f1 = __uint_as_float(e.y << 16);
          float f2 = __uint_as_float(e.y & 0xFFFF0000u);
          int hbase = (rr * GV + cc) * 3;
          atomicAdd(&hist[hbase + 0], f0);
          atomicAdd(&hist[hbase + 1], f1);
          atomicAdd(&hist[hbase + 2], f2);
        }
      }
    }
    __syncthreads();

    const vfloat4* hs = reinterpret_cast<const vfloat4*>(hist);
    for (int t = threadIdx.x; t < TR * ROWF4; t += 256) {
      int rr = t / ROWF4;
      int col = t - rr * ROWF4;
      int orow = rlo + rr;
      if ((unsigned)orow < GV) {    // clamp partial edge bands; exactly-once coverage
        vfloat4 v = hs[t];
        long g = g0 + (long)orow * (GV * 3) + col * 4;
        __builtin_nontemporal_store(v, reinterpret_cast<vfloat4*>(out + g));
        __builtin_nontemporal_store(v, reinterpret_cast<vfloat4*>(out + half + g));
      }
    }
  } else {
    // empty band: no hist zero/readback, store zeros straight from registers
    vfloat4 v = {0.0f, 0.0f, 0.0f, 0.0f};
    for (int t = threadIdx.x; t < TR * ROWF4; t += 256) {
      int rr = t / ROWF4;
      int col = t - rr * ROWF4;
      int orow = rlo + rr;
      if ((unsigned)orow < GV) {
        long g = g0 + (long)orow * (GV * 3) + col * 4;
        __builtin_nontemporal_store(v, reinterpret_cast<vfloat4*>(out + g));
        __builtin_nontemporal_store(v, reinterpret_cast<vfloat4*>(out + half + g));
      }
    }
  }
}

extern "C" void kernel_launch(void* const* d_in, const int* in_sizes, int n_in,
                              void* d_out, int out_size, void* d_ws, size_t ws_size,
                              hipStream_t stream) {
  const float* pc = (const float*)d_in[0];
  const float* feat = (const float*)d_in[1];
  float* out = (float*)d_out;

  char* ws = (char*)d_ws;
  int* cntArr = (int*)ws;                       // 32*16*128*4 = 256 KB
  int* mins = (int*)(ws + 262144);              // 32*16*2*4  = 4 KB
  uint2* buckets = (uint2*)(ws + 266240);       // 32*128*16*384*8 = 192 MB

  const long half = (long)BB * GV * GV * 3;     // 6,291,456 floats

  prep_kernel<<<dim3(BB * NCH), dim3(256), 0, stream>>>(pc, feat, mins, cntArr, buckets);
  tile_kernel<<<dim3(BB * NJ), dim3(256), 0, stream>>>(mins, cntArr, buckets, out, half);
}

// Round 3
// 87.082 us; speedup vs baseline: 1.0719x; 1.0719x over previous
//
#include <hip/hip_runtime.h>

// LatticeGen: permutohedral-lattice splat, reduced form.
// bary degenerates to [1,0,0]; out[b,r,c,ch] = sum_n feat[b,ch,n]*[bin(n)==(r,c)], duplicated.
// B=32, N=16384, grid G=256 (S=768, D1=3).
// Binning bit-matches numpy's plain (non-FMA) f32 arithmetic via
// `#pragma clang fp contract(off)` (__f*_rn are NOT contraction barriers — R2).
// R5: LDS-private output-tiled histogram. R8: offset-independent counting
// sort (ring keyed by absolute 4-row band of k0). R9/R11: 8B uint2 bf16
// payload entries. R10 FAILED: grid.sync ~70us on 8-XCD MI355X.
// R13: TR=4, NSLOT=128. R14: zero global coordination, no ws init.
// R15: tile chunk->wave ownership (no per-entry LDS search, no serial
// prefix); empty bands store zeros from registers. 92.4 -> 88.7 us.
// R16 FAILED (93.3): LDS slot-sorted staging in prep. prep runs at 2
// waves/SIMD — no TLP to hide the copy-out's per-wave serial chain of 32
// slot-iterations (~350 cy each ~= +4.6 us), and the problem it targeted
// was not real: each (chunk,slot) run avgs 8 entries = one aligned 64B
// line, fully accumulated in L2 before writeback (no write amplification).
// R17 (this round): revert prep to R15's direct scatter; keep R16's tile
// T==0 hoist (1280/2080 blocks skip the 12KB hist zeroing + one barrier).
// Floor model: ~77 us fixed harness (44 ws-poison + 8 out-poison + ~3
// restores + ~22 of tiny reset() dispatch overheads) + ~11-12 us kernel
// roofline (50MB out + 12MB in + ~8MB bucket R/W @ 6.3 TB/s) ~= 88 us.
// R15's 88.7 sits on this composite floor.

#define GV 256
#define NB 16384
#define BB 32
#define TR 4                         // rows per tile block
#define NSLOT 128                    // bucket ring slots per batch
#define NCH 16                       // prep chunks (blocks) per batch
#define NJ (GV / TR + 1)             // 65 tile blocks per batch (+1 for misalign)
#define TILE_FLOATS (TR * GV * 3)    // 3072 floats = 12 KB
#define ROWF4 (GV * 3 / 4)           // 192 float4 per output row
#define CAP 384                      // entries per (block,slot) sub-bucket
                                     //   (peak chunk-slot ~135 for this data; 2.8x margin)
#define PPT 4                        // points per thread in prep

typedef float vfloat4 __attribute__((ext_vector_type(4)));

__device__ __forceinline__ void lattice_point(const float* __restrict__ pc,
                                              long base, int n,
                                              int& k0o, int& k1o, int& r0o, int& r1o) {
#pragma clang fp contract(off)
  const float S6 = 2.449489742783178f;   // float32(sqrt(6.0))
  const float CA = 2.0f / S6;
  const float CB = -1.0f / S6;

  float p0 = pc[base + 0 * (long)NB + n];
  float p1 = pc[base + 1 * (long)NB + n];
  float p2 = pc[base + 2 * (long)NB + n];

  // elevated = E @ p: plain f32, left-to-right, no FMA — matches np.einsum
  float e0 = CA * p0 + CB * p1 + CB * p2;
  float e1 = CB * p0 + CA * p1 + CB * p2;
  float e2 = CB * p0 + CB * p1 + CA * p2;

  float q0 = rintf(e0 / 3.0f);
  float q1 = rintf(e1 / 3.0f);
  float q2 = rintf(e2 / 3.0f);
  int k0 = (int)q0, k1 = (int)q1, k2 = (int)q2;

  float m0 = e0 - q0 * 3.0f;
  float m1 = e1 - q1 * 3.0f;
  float m2 = e2 - q2 * 3.0f;

  // stable descending rank
  int rank0 = (m1 > m0) + (m2 > m0);
  int rank1 = (m0 > m1) + (m2 > m1) + (m0 == m1);
  int rs = k0 + k1 + k2;

  if (rs > 0) {
    int t = 3 - rs;
    if (rank0 >= t) { k0 -= 1; rank0 -= 3; }
    if (rank1 >= t) { k1 -= 1; rank1 -= 3; }
  } else if (rs < 0) {
    int t = -rs;
    if (rank0 < t) { k0 += 1; rank0 += 3; }
    if (rank1 < t) { k1 += 1; rank1 += 3; }
  }
  rank0 += rs; rank1 += rs;   // final rank in [0,2]

  k0o = k0; k1o = k1; r0o = rank0; r1o = rank1;   // gl = 3*k
}

// off (= min_n 3*k_i - rank_i) -> shift in k units: s = (off+pick)/3, exact.
__device__ __forceinline__ int k_shift(int off) {
  int pick = ((-off) % 3 + 3) % 3;   // off+pick is an exact multiple of 3
  return (off + pick) / 3;
}

__device__ __forceinline__ unsigned int bf16_rne(float f) {
  unsigned int u = __float_as_uint(f);
  return (u + 0x7FFFu + ((u >> 16) & 1u)) >> 16;
}

// Pass 1: lattice -> per-block mins + counting-sort into private sub-buckets.
// 512 blocks; block (b,chunk) owns 1024 consecutive points, 4/thread.
// Direct scattered 8B stores (R15 form): each (chunk,slot) run avgs one
// aligned 64B line, accumulated in L2 — no amplification; and at 2
// waves/SIMD occupancy any added serial LDS chain costs ~us (R16 lesson).
// Writes: buckets[b][m][chunk][0..cnt), cntArr[b][chunk][m] (all 128),
// mins[b][chunk][0..1]. Everything read later is written here — no init.
__global__ void __launch_bounds__(256) prep_kernel(const float* __restrict__ pc,
                                                   const float* __restrict__ feat,
                                                   int* __restrict__ mins,
                                                   int* __restrict__ cntArr,
                                                   uint2* __restrict__ buckets) {
  int i = blockIdx.x;
  int b = (i & 7) + 8 * ((i >> 3) & 3);   // XCD-affinity: same-batch blocks share i%8
  int chunk = i >> 5;                     // 0..15
  int n0 = chunk * 1024 + threadIdx.x;

  __shared__ unsigned int cnt[NSLOT];
  __shared__ int s0w[4], s1w[4];
  if (threadIdx.x < NSLOT) cnt[threadIdx.x] = 0;
  __syncthreads();

  long pcB = (long)b * 3 * NB;
  long bktB = ((long)b * NSLOT * NCH + chunk) * CAP;  // + m*NCH*CAP below
  int mloc0 = 0x7FFFFFFF, mloc1 = 0x7FFFFFFF;

#pragma unroll
  for (int p = 0; p < PPT; ++p) {
    int n = n0 + p * 256;
    int k0, k1, r0, r1;
    lattice_point(pc, pcB, n, k0, k1, r0, r1);

    int kb = k0 + 8192;                   // >= 0
    int m = (kb >> 2) & (NSLOT - 1);      // 4-row-band ring slot

    long fbB = pcB + n;
    unsigned int b0 = bf16_rne(feat[fbB]);
    unsigned int b1 = bf16_rne(feat[fbB + NB]);
    unsigned int b2 = bf16_rne(feat[fbB + 2 * NB]);
    uint2 ent;
    // meta: kb&3 (2b) | k1+512 (10b) | pad (1b) | bf16(f0) (16b)
    ent.x = (unsigned int)(kb & 3) | ((unsigned int)(k1 + 512) << 2) | (b0 << 13);
    ent.y = b1 | (b2 << 16);

    unsigned int sl = atomicAdd(&cnt[m], 1u);
    buckets[bktB + (long)m * (NCH * CAP) + sl] = ent;   // store immediately

    mloc0 = min(mloc0, 3 * k0 - r0);
    mloc1 = min(mloc1, 3 * k1 - r1);
  }

  // block-level mins of (3k - rank)
  for (int off = 32; off > 0; off >>= 1) {
    mloc0 = min(mloc0, __shfl_down(mloc0, off));
    mloc1 = min(mloc1, __shfl_down(mloc1, off));
  }
  int lane = threadIdx.x & 63, wv = threadIdx.x >> 6;
  if (lane == 0) { s0w[wv] = mloc0; s1w[wv] = mloc1; }
  __syncthreads();   // cnt totals final; s0w/s1w visible
  if (threadIdx.x == 0) {
    mins[(b * NCH + chunk) * 2 + 0] = min(min(s0w[0], s0w[1]), min(s0w[2], s0w[3]));
    mins[(b * NCH + chunk) * 2 + 1] = min(min(s1w[0], s1w[1]), min(s1w[2], s1w[3]));
  }
  if (threadIdx.x < NSLOT)
    cntArr[(b * NCH + chunk) * NSLOT + threadIdx.x] = (int)cnt[threadIdx.x];
}

// Pass 2: one block per (batch, absolute 4-row band). Wave wv owns chunks
// {wv, wv+4, wv+8, wv+12}; plain strided scan per chunk (no per-entry
// search, no prefix sum). LDS hist; float4 store x2. T==0 blocks (most)
// skip the hist entirely and store zeros from registers.
__global__ void __launch_bounds__(256) tile_kernel(const int* __restrict__ mins,
                                                   const int* __restrict__ cntArr,
                                                   const uint2* __restrict__ buckets,
                                                   float* __restrict__ out, long half) {
  __shared__ float hist[TILE_FLOATS];  // [TR][GV][3], 12 KB
  __shared__ int sOff[2];
  __shared__ int scnt[NCH];

  int i = blockIdx.x;                    // 0..BB*NJ-1
  int w = i & 31;
  int b = (w & 7) + 8 * ((w >> 3) & 3);  // matches prep's i%8 XCD affinity
  int j = i >> 5;                        // 0..NJ-1

  // reduce the 16 per-block mins (threads 0,1: one dim each)
  if (threadIdx.x < 2) {
    int mn = 0x7FFFFFFF;
#pragma unroll
    for (int c = 0; c < NCH; ++c)
      mn = min(mn, mins[(b * NCH + c) * 2 + threadIdx.x]);
    sOff[threadIdx.x] = mn;
  }
  __syncthreads();                       // sOff visible (m depends on it)

  int s0b = k_shift(sOff[0]) + 8192;     // row shift in k units, biased
  int s1b = k_shift(sOff[1]) + 512;      // col shift, biased to match entry pack
  int kt = (s0b >> 2) + j;               // this block's absolute 4-row band
  int m = kt & (NSLOT - 1);
  int rlo = 4 * kt - s0b;                // output row of hist row 0, in [-3, 256+3]

  if (threadIdx.x < NCH)                 // stage chunk counts
    scnt[threadIdx.x] = cntArr[(b * NCH + threadIdx.x) * NSLOT + m];
  __syncthreads();

  int T = 0;
#pragma unroll
  for (int c = 0; c < NCH; ++c) T += scnt[c];   // cheap broadcast reads

  long g0 = ((long)b * GV) * GV * 3;

  if (T > 0) {                           // block-uniform branch: barriers legal
    for (int t = threadIdx.x; t < TILE_FLOATS; t += 256) hist[t] = 0.0f;
    __syncthreads();

    int wv = threadIdx.x >> 6, lane = threadIdx.x & 63;
    long base = ((long)b * NSLOT + m) * (NCH * CAP);
#pragma unroll
    for (int cq = 0; cq < NCH / 4; ++cq) {
      int c = wv + cq * 4;
      int cnt = scnt[c];                 // wave-uniform LDS broadcast
      long cb = base + (long)c * CAP;
      for (int t = lane; t < cnt; t += 64) {
        uint2 e = buckets[cb + t];       // coalesced 8B within the run
        int rr = e.x & 3;
        int cc = (int)((e.x >> 2) & 1023) - s1b;  // >= 0 by construction of off1
        if (cc < GV) {                            // JAX scatter 'drop'
          float f0 = __uint_as_float((e.x >> 13) << 16);
          float f1 = __uint_as_float(e.y << 16);
          float f2 = __uint_as_float(e.y & 0xFFFF0000u);
          int hbase = (rr * GV + cc) * 3;
          atomicAdd(&hist[hbase + 0], f0);
          atomicAdd(&hist[hbase + 1], f1);
          atomicAdd(&hist[hbase + 2], f2);
        }
      }
    }
    __syncthreads();

    const vfloat4* hs = reinterpret_cast<const vfloat4*>(hist);
    for (int t = threadIdx.x; t < TR * ROWF4; t += 256) {
      int rr = t / ROWF4;
      int col = t - rr * ROWF4;
      int orow = rlo + rr;
      if ((unsigned)orow < GV) {    // clamp partial edge bands; exactly-once coverage
        vfloat4 v = hs[t];
        long g = g0 + (long)orow * (GV * 3) + col * 4;
        __builtin_nontemporal_store(v, reinterpret_cast<vfloat4*>(out + g));
        __builtin_nontemporal_store(v, reinterpret_cast<vfloat4*>(out + half + g));
      }
    }
  } else {
    // empty band: no hist zero/readback, store zeros straight from registers
    vfloat4 v = {0.0f, 0.0f, 0.0f, 0.0f};
    for (int t = threadIdx.x; t < TR * ROWF4; t += 256) {
      int rr = t / ROWF4;
      int col = t - rr * ROWF4;
      int orow = rlo + rr;
      if ((unsigned)orow < GV) {
        long g = g0 + (long)orow * (GV * 3) + col * 4;
        __builtin_nontemporal_store(v, reinterpret_cast<vfloat4*>(out + g));
        __builtin_nontemporal_store(v, reinterpret_cast<vfloat4*>(out + half + g));
      }
    }
  }
}

extern "C" void kernel_launch(void* const* d_in, const int* in_sizes, int n_in,
                              void* d_out, int out_size, void* d_ws, size_t ws_size,
                              hipStream_t stream) {
  const float* pc = (const float*)d_in[0];
  const float* feat = (const float*)d_in[1];
  float* out = (float*)d_out;

  char* ws = (char*)d_ws;
  int* cntArr = (int*)ws;                       // 32*16*128*4 = 256 KB
  int* mins = (int*)(ws + 262144);              // 32*16*2*4  = 4 KB
  uint2* buckets = (uint2*)(ws + 266240);       // 32*128*16*384*8 = 192 MB

  const long half = (long)BB * GV * GV * 3;     // 6,291,456 floats

  prep_kernel<<<dim3(BB * NCH), dim3(256), 0, stream>>>(pc, feat, mins, cntArr, buckets);
  tile_kernel<<<dim3(BB * NJ), dim3(256), 0, stream>>>(mins, cntArr, buckets, out, half);
}